// Round 10
// baseline (317.926 us; speedup 1.0000x reference)
//
#include <hip/hip_runtime.h>

#define NNODES 50000
#define NEDGES 800000
#define NF 96
#define NF4 24              // float4 per f32 row
#define NBW 8               // nodes per wave (fused)
#define WPB 8               // waves per block (512 threads, fused)
#define FTHREADS 512
#define ACC_STRIDE 97       // Acc row stride (floats)
#define NPW 16              // nodes per wave (node MLP)
#define TSTRIDE 100         // h1 transpose tile stride (floats, 16B-aligned)

typedef short bf16x8 __attribute__((ext_vector_type(8)));
typedef float f32x4 __attribute__((ext_vector_type(4)));

__device__ inline unsigned pk_bf16(float a, float b) {
    union { __bf16 h[2]; unsigned u; } q;
    q.h[0] = (__bf16)a; q.h[1] = (__bf16)b;
    return q.u;
}
__device__ inline unsigned short bf16_1(float a) {
    union { __bf16 h; unsigned short u; } q;
    q.h = (__bf16)a;
    return q.u;
}
__device__ inline bf16x8 cvt8(float4 a, float4 b) {
    union { unsigned u[4]; bf16x8 v; } q;
    q.u[0] = pk_bf16(a.x, a.y); q.u[1] = pk_bf16(a.z, a.w);
    q.u[2] = pk_bf16(b.x, b.y); q.u[3] = pk_bf16(b.z, b.w);
    return q.v;
}
__device__ inline int imin(int a, int b) { return a < b ? a : b; }

// ---------------------------------------------------------------------------
// prep: blocks 0/1/2 pack We/W1/W2 into MFMA B-fragment order (bf16);
// remaining blocks do the dst histogram.
// pack[((ot*3+kb)*64+l)*8+j] = bf16(W[(ot*16+(l&15))*96 + kb*32+(l>>4)*8+j])
// ---------------------------------------------------------------------------
__global__ __launch_bounds__(256) void prep_hist(
    const float* __restrict__ We, const float* __restrict__ W1,
    const float* __restrict__ W2, unsigned short* __restrict__ Wep,
    unsigned short* __restrict__ W1p, unsigned short* __restrict__ W2p,
    const int* __restrict__ ei, int* __restrict__ deg) {
    int b = blockIdx.x;
    if (b < 3) {
        const float* S = (b == 0) ? We : (b == 1) ? W1 : W2;
        unsigned short* D = (b == 0) ? Wep : (b == 1) ? W1p : W2p;
        for (int i = threadIdx.x; i < 18 * 64 * 8; i += blockDim.x) {
            int f = i >> 9, rem = i & 511;
            int l = rem >> 3, j = rem & 7;
            int ot = f / 3, kb = f % 3;
            int o = ot * 16 + (l & 15);
            int k = kb * 32 + ((l >> 4) << 3) + j;
            D[i] = bf16_1(S[o * NF + k]);
        }
    } else {
        int e = (b - 3) * 256 + threadIdx.x;
        if (e < NEDGES) atomicAdd(&deg[ei[NEDGES + e]], 1);
    }
}

// ---------------------------------------------------------------------------
// 3-phase multi-block scan + slot fill (int atomics only)
// ---------------------------------------------------------------------------
#define SCAN_BLOCKS 196  // ceil(50000 / 256)

__global__ __launch_bounds__(256) void scan_partial(const int* __restrict__ deg,
                                                    int* __restrict__ bsum) {
    __shared__ int red[256];
    int t = threadIdx.x;
    int i = blockIdx.x * 256 + t;
    red[t] = (i < NNODES) ? deg[i] : 0;
    __syncthreads();
    for (int off = 128; off; off >>= 1) {
        if (t < off) red[t] += red[t + off];
        __syncthreads();
    }
    if (t == 0) bsum[blockIdx.x] = red[0];
}

__global__ __launch_bounds__(256) void scan_bsum(const int* __restrict__ bsum,
                                                 int* __restrict__ bstart) {
    __shared__ int s[256];
    int t = threadIdx.x;
    s[t] = (t < SCAN_BLOCKS) ? bsum[t] : 0;
    __syncthreads();
    for (int off = 1; off < 256; off <<= 1) {
        int v = (t >= off) ? s[t - off] : 0;
        __syncthreads();
        s[t] += v;
        __syncthreads();
    }
    bstart[t] = (t == 0) ? 0 : s[t - 1];  // exclusive
}

__global__ __launch_bounds__(256) void scan_write(const int* __restrict__ deg,
                                                  const int* __restrict__ bstart,
                                                  int* __restrict__ start,
                                                  int* __restrict__ cursor) {
    __shared__ int s[256];
    int t = threadIdx.x;
    int i = blockIdx.x * 256 + t;
    int d = (i < NNODES) ? deg[i] : 0;
    s[t] = d;
    __syncthreads();
    for (int off = 1; off < 256; off <<= 1) {
        int v = (t >= off) ? s[t - off] : 0;
        __syncthreads();
        s[t] += v;
        __syncthreads();
    }
    int excl = ((t == 0) ? 0 : s[t - 1]) + bstart[blockIdx.x];
    if (i < NNODES) {
        start[i] = excl;
        cursor[i] = excl;
        if (i == NNODES - 1) start[NNODES] = excl + d;
    }
}

__global__ void fill_kernel(const int* __restrict__ ei, int* __restrict__ cursor,
                            int* __restrict__ eidx, int* __restrict__ srcs,
                            int* __restrict__ snode) {
    int e = blockIdx.x * blockDim.x + threadIdx.x;
    if (e < NEDGES) {
        int d = ei[NEDGES + e];
        int p = atomicAdd(&cursor[d], 1);
        eidx[p] = e;
        srcs[p] = ei[e];
        snode[p] = d;
    }
}

// ---------------------------------------------------------------------------
// Wave-autonomous fused edge-GEMM + segment-sum, branchless software pipeline.
// 512-thread blocks: 8 waves amortize one Wlds copy -> 43.3 KB LDS/block,
// 3 blocks/CU = 24 waves/CU. Wave owns NBW=8 nodes (CSR [s0,s1)).
// All prefetches unconditional, indices clamped to s1-1 (SSA-clean).
// ---------------------------------------------------------------------------
__global__ __launch_bounds__(FTHREADS) void fused_edge_aggr(
    const float* __restrict__ attr, const int* __restrict__ eidx,
    const int* __restrict__ srcs_g, const int* __restrict__ snode_g,
    const int* __restrict__ start, const float* __restrict__ x,
    const unsigned short* __restrict__ Wpack, const float* __restrict__ be,
    const float* __restrict__ epsp, float* __restrict__ h) {
    __shared__ short Wlds[18 * 64 * 8];             // 18,432 B
    __shared__ float Acc[WPB][NBW][ACC_STRIDE];     // 24,832 B

    const int t = threadIdx.x;
    {
        const uint4* wsrc = reinterpret_cast<const uint4*>(Wpack);
        uint4* wdst = reinterpret_cast<uint4*>(Wlds);
        for (int i = t; i < 18 * 64; i += FTHREADS) wdst[i] = wsrc[i];
        float* accf = &Acc[0][0][0];
        for (int i = t; i < WPB * NBW * ACC_STRIDE; i += FTHREADS) accf[i] = 0.f;
    }
    __syncthreads();

    const int w = t >> 6;             // wave 0..7
    const int lane = t & 63;
    const int l15 = lane & 15, l4 = lane >> 4;
    const int n0w = (blockIdx.x * WPB + w) * NBW;
    if (n0w >= NNODES) return;
    const int s0 = start[n0w], s1 = start[n0w + NBW];
    float* AccW = &Acc[w][0][0];

    float bias[6];
#pragma unroll
    for (int ot = 0; ot < 6; ++ot) bias[ot] = be[ot * 16 + l15];

    const float4* a4 = reinterpret_cast<const float4*>(attr);
    const int nt = (s1 - s0 + 15) >> 4;

    if (nt > 0) {
        const int smax = s1 - 1;

        // ---- prologue: tile 0 data + tile 1 indices (all clamped) ----
        float4 a_cur[6];
        int m_cur[4], sv_cur[4], m_nxt[4], sv_nxt[4], ev_nxt;
        {
            int ev0 = eidx[imin(s0 + l15, smax)];
            const float4* ar = a4 + (size_t)ev0 * NF4 + l4 * 2;
            a_cur[0] = ar[0];  a_cur[1] = ar[1];
            a_cur[2] = ar[8];  a_cur[3] = ar[9];
            a_cur[4] = ar[16]; a_cur[5] = ar[17];
            ev_nxt = eidx[imin(s0 + 16 + l15, smax)];
#pragma unroll
            for (int r = 0; r < 4; ++r) {
                m_cur[r]  = snode_g[imin(s0 + l4 * 4 + r, smax)];
                sv_cur[r] = srcs_g[imin(s0 + l4 * 4 + r, smax)];
                m_nxt[r]  = snode_g[imin(s0 + 16 + l4 * 4 + r, smax)];
                sv_nxt[r] = srcs_g[imin(s0 + 16 + l4 * 4 + r, smax)];
            }
        }

        for (int tt = 0; tt < nt; ++tt) {
            const int base = s0 + 16 * tt;

            // ---- 1. consume current attr regs ----
            bf16x8 af[3];
            af[0] = cvt8(a_cur[0], a_cur[1]);
            af[1] = cvt8(a_cur[2], a_cur[3]);
            af[2] = cvt8(a_cur[4], a_cur[5]);

            // ---- 2. reissue attr loads for tile tt+1 (unconditional) ----
            {
                const float4* ar = a4 + (size_t)ev_nxt * NF4 + l4 * 2;
                a_cur[0] = ar[0];  a_cur[1] = ar[1];
                a_cur[2] = ar[8];  a_cur[3] = ar[9];
                a_cur[4] = ar[16]; a_cur[5] = ar[17];
            }

            // ---- 3. eidx for tile tt+2 ----
            ev_nxt = eidx[imin(base + 32 + l15, smax)];

            // ---- 4. current masks + x gathers (pre-MFMA) ----
            int m[4];
            float xe[4][6];
#pragma unroll
            for (int r = 0; r < 4; ++r) {
                m[r] = ((base + l4 * 4 + r) < s1) ? (m_cur[r] - n0w) : -1;
                const float* xr = x + (size_t)sv_cur[r] * NF + l15;
#pragma unroll
                for (int ot = 0; ot < 6; ++ot) xe[r][ot] = xr[ot * 16];
            }

            // ---- 5. rotate index state; load tile tt+2 indices ----
#pragma unroll
            for (int r = 0; r < 4; ++r) { m_cur[r] = m_nxt[r]; sv_cur[r] = sv_nxt[r]; }
#pragma unroll
            for (int r = 0; r < 4; ++r) {
                m_nxt[r]  = snode_g[imin(base + 32 + l4 * 4 + r, smax)];
                sv_nxt[r] = srcs_g[imin(base + 32 + l4 * 4 + r, smax)];
            }

            // ---- 6. 18 MFMA: D[e][o] (setprio: wave-autonomous regime) ----
            __builtin_amdgcn_s_setprio(1);
            f32x4 acc[6];
#pragma unroll
            for (int ot = 0; ot < 6; ++ot) {
                f32x4 c = {bias[ot], bias[ot], bias[ot], bias[ot]};
#pragma unroll
                for (int kb = 0; kb < 3; ++kb) {
                    bf16x8 bf = *reinterpret_cast<const bf16x8*>(
                        &Wlds[((ot * 3 + kb) * 64 + lane) * 8]);
                    c = __builtin_amdgcn_mfma_f32_16x16x32_bf16(af[kb], bf, c,
                                                                0, 0, 0);
                }
                acc[ot] = c;
            }
            __builtin_amdgcn_s_setprio(0);

            // ---- 7. epilogue: relu + in-lane segmented reduce + ds_add ----
            const bool c1 = (m[1] == m[0]);
            const bool c2 = (m[2] == m[1]);
            const bool c3 = (m[3] == m[2]);
#pragma unroll
            for (int ot = 0; ot < 6; ++ot) {
                const int o = ot * 16 + l15;
                float v0 = fmaxf(acc[ot][0] + xe[0][ot], 0.f);
                float v1 = fmaxf(acc[ot][1] + xe[1][ot], 0.f);
                float v2 = fmaxf(acc[ot][2] + xe[2][ot], 0.f);
                float v3 = fmaxf(acc[ot][3] + xe[3][ot], 0.f);
                float run = v0;
                if (!c1) {
                    if (m[0] >= 0) atomicAdd(&AccW[m[0] * ACC_STRIDE + o], run);
                    run = 0.f;
                }
                run += v1;
                if (!c2) {
                    if (m[1] >= 0) atomicAdd(&AccW[m[1] * ACC_STRIDE + o], run);
                    run = 0.f;
                }
                run += v2;
                if (!c3) {
                    if (m[2] >= 0) atomicAdd(&AccW[m[2] * ACC_STRIDE + o], run);
                    run = 0.f;
                }
                run += v3;
                if (m[3] >= 0) atomicAdd(&AccW[m[3] * ACC_STRIDE + o], run);
            }
        }
    }

    // ---- drain this wave's ds_adds, then write h (wave-private) ----
    asm volatile("s_waitcnt lgkmcnt(0)" ::: "memory");
    __builtin_amdgcn_sched_barrier(0);
    const float ep = 1.0f + *epsp;
#pragma unroll
    for (int i = 0; i < NBW * NF / 64; ++i) {  // 12
        int item = lane + 64 * i;
        int n = item / NF, f = item % NF;
        float a = AccW[n * ACC_STRIDE + f];
        size_t g = (size_t)(n0w + n) * NF + f;
        h[g] = fmaf(ep, x[g], a);
    }
}

// ---------------------------------------------------------------------------
// Node MLP via bf16 MFMA. Wave owns NPW=16 nodes (contiguous, dense rows).
//   GEMM1: A = h rows (cvt bf16), B = W1pack (LDS) -> h1[16n][96o]
//   relu -> LDS transpose T -> A2 frags -> GEMM2 vs W2pack -> out
// ---------------------------------------------------------------------------
__global__ __launch_bounds__(256) void node_mfma(
    const float* __restrict__ h, const unsigned short* __restrict__ W1p,
    const float* __restrict__ b1, const unsigned short* __restrict__ W2p,
    const float* __restrict__ b2, float* __restrict__ out) {
    __shared__ short W1lds[18 * 64 * 8];          // 18,432 B
    __shared__ short W2lds[18 * 64 * 8];          // 18,432 B
    __shared__ float T[4][NPW][TSTRIDE];          // 25,600 B

    const int t = threadIdx.x;
    {
        const uint4* s1v = reinterpret_cast<const uint4*>(W1p);
        const uint4* s2v = reinterpret_cast<const uint4*>(W2p);
        uint4* d1 = reinterpret_cast<uint4*>(W1lds);
        uint4* d2 = reinterpret_cast<uint4*>(W2lds);
        for (int i = t; i < 18 * 64; i += 256) { d1[i] = s1v[i]; d2[i] = s2v[i]; }
    }
    __syncthreads();

    const int w = t >> 6;
    const int lane = t & 63;
    const int l15 = lane & 15, l4 = lane >> 4;
    const int n0 = (blockIdx.x * 4 + w) * NPW;
    if (n0 >= NNODES) return;

    // A-frags: h row n0+l15, k-span kb*32 + l4*8
    const float4* hrow = reinterpret_cast<const float4*>(h + (size_t)(n0 + l15) * NF);
    bf16x8 af[3];
#pragma unroll
    for (int kb = 0; kb < 3; ++kb)
        af[kb] = cvt8(hrow[kb * 8 + l4 * 2], hrow[kb * 8 + l4 * 2 + 1]);

    // GEMM1 + relu -> T
    float* Tw = &T[w][0][0];
#pragma unroll
    for (int ot = 0; ot < 6; ++ot) {
        float b = b1[ot * 16 + l15];
        f32x4 c = {b, b, b, b};
#pragma unroll
        for (int kb = 0; kb < 3; ++kb) {
            bf16x8 bf = *reinterpret_cast<const bf16x8*>(
                &W1lds[((ot * 3 + kb) * 64 + lane) * 8]);
            c = __builtin_amdgcn_mfma_f32_16x16x32_bf16(af[kb], bf, c, 0, 0, 0);
        }
#pragma unroll
        for (int r = 0; r < 4; ++r)
            Tw[(l4 * 4 + r) * TSTRIDE + ot * 16 + l15] = fmaxf(c[r], 0.f);
    }

    // wave-local LDS write->read ordering
    asm volatile("s_waitcnt lgkmcnt(0)" ::: "memory");
    __builtin_amdgcn_sched_barrier(0);

    // A2-frags from T (row l15), then GEMM2 -> out
    bf16x8 af2[3];
#pragma unroll
    for (int kb = 0; kb < 3; ++kb) {
        const float4* tr = reinterpret_cast<const float4*>(
            &Tw[l15 * TSTRIDE + kb * 32 + l4 * 8]);
        af2[kb] = cvt8(tr[0], tr[1]);
    }
#pragma unroll
    for (int ot = 0; ot < 6; ++ot) {
        float b = b2[ot * 16 + l15];
        f32x4 c = {b, b, b, b};
#pragma unroll
        for (int kb = 0; kb < 3; ++kb) {
            bf16x8 bf = *reinterpret_cast<const bf16x8*>(
                &W2lds[((ot * 3 + kb) * 64 + lane) * 8]);
            c = __builtin_amdgcn_mfma_f32_16x16x32_bf16(af2[kb], bf, c, 0, 0, 0);
        }
#pragma unroll
        for (int r = 0; r < 4; ++r)
            out[(size_t)(n0 + l4 * 4 + r) * NF + ot * 16 + l15] = c[r];
    }
}

// ---------------------------------------------------------------------------
extern "C" void kernel_launch(void* const* d_in, const int* in_sizes, int n_in,
                              void* d_out, int out_size, void* d_ws, size_t ws_size,
                              hipStream_t stream) {
    const float* x   = (const float*)d_in[0];
    const int*   ei  = (const int*)d_in[1];
    const float* ea  = (const float*)d_in[2];
    const float* We  = (const float*)d_in[3];
    const float* be  = (const float*)d_in[4];
    const float* eps = (const float*)d_in[5];
    const float* W1  = (const float*)d_in[6];
    const float* b1  = (const float*)d_in[7];
    const float* W2  = (const float*)d_in[8];
    const float* b2  = (const float*)d_in[9];
    float* out = (float*)d_out;

    // ws layout
    float* h    = (float*)d_ws;                          // 50000*96 f (19.2 MB)
    unsigned short* Wep = (unsigned short*)(h + (size_t)NNODES * NF);  // 9216
    unsigned short* W1p = Wep + 18 * 64 * 8;             // 9216
    unsigned short* W2p = W1p + 18 * 64 * 8;             // 9216
    int* deg    = (int*)(W2p + 18 * 64 * 8);             // 50000
    int* start  = deg + NNODES;                          // 50001
    int* cursor = start + NNODES + 1;                    // 50000
    int* eidx   = cursor + NNODES;                       // 800000 (+pad)
    int* srcs   = eidx + NEDGES + 64;                    // 800000 (+pad)
    int* snode  = srcs + NEDGES + 64;                    // 800000 (+pad)
    int* bsum   = snode + NEDGES + 64;                   // 256
    int* bstart = bsum + 256;                            // 256

    hipMemsetAsync(deg, 0, NNODES * sizeof(int), stream);
    prep_hist<<<3 + (NEDGES + 255) / 256, 256, 0, stream>>>(We, W1, W2, Wep, W1p,
                                                            W2p, ei, deg);
    scan_partial<<<SCAN_BLOCKS, 256, 0, stream>>>(deg, bsum);
    scan_bsum<<<1, 256, 0, stream>>>(bsum, bstart);
    scan_write<<<SCAN_BLOCKS, 256, 0, stream>>>(deg, bstart, start, cursor);
    fill_kernel<<<(NEDGES + 255) / 256, 256, 0, stream>>>(ei, cursor, eidx, srcs,
                                                          snode);
    int nwaves = (NNODES + NBW - 1) / NBW;               // 6250
    int nblocks = (nwaves + WPB - 1) / WPB;              // 782
    fused_edge_aggr<<<nblocks, FTHREADS, 0, stream>>>(ea, eidx, srcs, snode, start,
                                                      x, Wep, be, eps, h);
    int nwaves2 = (NNODES + NPW - 1) / NPW;              // 3125
    int nblocks2 = (nwaves2 + 3) / 4;                    // 782
    node_mfma<<<nblocks2, 256, 0, stream>>>(h, W1p, b1, W2p, b2, out);
}

// Round 11
// 275.652 us; speedup vs baseline: 1.1534x; 1.1534x over previous
//
#include <hip/hip_runtime.h>

#define NNODES 50000
#define NEDGES 800000
#define NF 96
#define NF4 24              // float4 per f32 row
#define NBW 8               // nodes per wave (fused)
#define WPB 4               // waves per block (256 threads)
#define ACC_STRIDE 97       // Acc row stride (floats)
#define NPW 16              // nodes per wave (node MLP)
#define TSTRIDE 100         // h1 transpose tile stride (floats, 16B-aligned)

typedef short bf16x8 __attribute__((ext_vector_type(8)));
typedef float f32x4 __attribute__((ext_vector_type(4)));

__device__ inline unsigned pk_bf16(float a, float b) {
    union { __bf16 h[2]; unsigned u; } q;
    q.h[0] = (__bf16)a; q.h[1] = (__bf16)b;
    return q.u;
}
__device__ inline unsigned short bf16_1(float a) {
    union { __bf16 h; unsigned short u; } q;
    q.h = (__bf16)a;
    return q.u;
}
__device__ inline bf16x8 cvt8(float4 a, float4 b) {
    union { unsigned u[4]; bf16x8 v; } q;
    q.u[0] = pk_bf16(a.x, a.y); q.u[1] = pk_bf16(a.z, a.w);
    q.u[2] = pk_bf16(b.x, b.y); q.u[3] = pk_bf16(b.z, b.w);
    return q.v;
}
__device__ inline int imin(int a, int b) { return a < b ? a : b; }

// ---------------------------------------------------------------------------
// prep: blocks 0/1/2 pack We/W1/W2 into MFMA B-fragment order (bf16);
// remaining blocks do the dst histogram.
// pack[((ot*3+kb)*64+l)*8+j] = bf16(W[(ot*16+(l&15))*96 + kb*32+(l>>4)*8+j])
// ---------------------------------------------------------------------------
__global__ __launch_bounds__(256) void prep_hist(
    const float* __restrict__ We, const float* __restrict__ W1,
    const float* __restrict__ W2, unsigned short* __restrict__ Wep,
    unsigned short* __restrict__ W1p, unsigned short* __restrict__ W2p,
    const int* __restrict__ ei, int* __restrict__ deg) {
    int b = blockIdx.x;
    if (b < 3) {
        const float* S = (b == 0) ? We : (b == 1) ? W1 : W2;
        unsigned short* D = (b == 0) ? Wep : (b == 1) ? W1p : W2p;
        for (int i = threadIdx.x; i < 18 * 64 * 8; i += blockDim.x) {
            int f = i >> 9, rem = i & 511;
            int l = rem >> 3, j = rem & 7;
            int ot = f / 3, kb = f % 3;
            int o = ot * 16 + (l & 15);
            int k = kb * 32 + ((l >> 4) << 3) + j;
            D[i] = bf16_1(S[o * NF + k]);
        }
    } else {
        int e = (b - 3) * 256 + threadIdx.x;
        if (e < NEDGES) atomicAdd(&deg[ei[NEDGES + e]], 1);
    }
}

// ---------------------------------------------------------------------------
// 3-phase multi-block scan + slot fill (int atomics only)
// ---------------------------------------------------------------------------
#define SCAN_BLOCKS 196  // ceil(50000 / 256)

__global__ __launch_bounds__(256) void scan_partial(const int* __restrict__ deg,
                                                    int* __restrict__ bsum) {
    __shared__ int red[256];
    int t = threadIdx.x;
    int i = blockIdx.x * 256 + t;
    red[t] = (i < NNODES) ? deg[i] : 0;
    __syncthreads();
    for (int off = 128; off; off >>= 1) {
        if (t < off) red[t] += red[t + off];
        __syncthreads();
    }
    if (t == 0) bsum[blockIdx.x] = red[0];
}

__global__ __launch_bounds__(256) void scan_bsum(const int* __restrict__ bsum,
                                                 int* __restrict__ bstart) {
    __shared__ int s[256];
    int t = threadIdx.x;
    s[t] = (t < SCAN_BLOCKS) ? bsum[t] : 0;
    __syncthreads();
    for (int off = 1; off < 256; off <<= 1) {
        int v = (t >= off) ? s[t - off] : 0;
        __syncthreads();
        s[t] += v;
        __syncthreads();
    }
    bstart[t] = (t == 0) ? 0 : s[t - 1];  // exclusive
}

__global__ __launch_bounds__(256) void scan_write(const int* __restrict__ deg,
                                                  const int* __restrict__ bstart,
                                                  int* __restrict__ start,
                                                  int* __restrict__ cursor) {
    __shared__ int s[256];
    int t = threadIdx.x;
    int i = blockIdx.x * 256 + t;
    int d = (i < NNODES) ? deg[i] : 0;
    s[t] = d;
    __syncthreads();
    for (int off = 1; off < 256; off <<= 1) {
        int v = (t >= off) ? s[t - off] : 0;
        __syncthreads();
        s[t] += v;
        __syncthreads();
    }
    int excl = ((t == 0) ? 0 : s[t - 1]) + bstart[blockIdx.x];
    if (i < NNODES) {
        start[i] = excl;
        cursor[i] = excl;
        if (i == NNODES - 1) start[NNODES] = excl + d;
    }
}

// fill: eidx[p] = edge id; ss[p] = (src, dst) packed
__global__ void fill_kernel(const int* __restrict__ ei, int* __restrict__ cursor,
                            int* __restrict__ eidx, int2* __restrict__ ss) {
    int e = blockIdx.x * blockDim.x + threadIdx.x;
    if (e < NEDGES) {
        int d = ei[NEDGES + e];
        int p = atomicAdd(&cursor[d], 1);
        eidx[p] = e;
        ss[p] = make_int2(ei[e], d);
    }
}

// ---------------------------------------------------------------------------
// Wave-autonomous fused edge-GEMM + segment-sum, branchless software pipeline.
// R11: xe (x[src] gathers) double-buffered one tile ahead, like attr.
// Pipeline state entering iteration tt:
//   a_cur  = attr data, tile tt       ev_nxt  = eidx lanes, tile tt+1
//   ss_cur = (src,dst), tile tt       ss_nxt  = (src,dst), tile tt+1
//   xe_cur = x data, tile tt
// ---------------------------------------------------------------------------
__global__ __launch_bounds__(256) void fused_edge_aggr(
    const float* __restrict__ attr, const int* __restrict__ eidx,
    const int2* __restrict__ ss_g, const int* __restrict__ start,
    const float* __restrict__ x, const unsigned short* __restrict__ Wpack,
    const float* __restrict__ be, const float* __restrict__ epsp,
    float* __restrict__ h) {
    __shared__ short Wlds[18 * 64 * 8];             // 18,432 B
    __shared__ float Acc[WPB][NBW][ACC_STRIDE];     // 12,416 B

    const int t = threadIdx.x;
    {
        const uint4* wsrc = reinterpret_cast<const uint4*>(Wpack);
        uint4* wdst = reinterpret_cast<uint4*>(Wlds);
        for (int i = t; i < 18 * 64; i += 256) wdst[i] = wsrc[i];
        float* accf = &Acc[0][0][0];
        for (int i = t; i < WPB * NBW * ACC_STRIDE; i += 256) accf[i] = 0.f;
    }
    __syncthreads();

    const int w = t >> 6;
    const int lane = t & 63;
    const int l15 = lane & 15, l4 = lane >> 4;
    const int n0w = (blockIdx.x * WPB + w) * NBW;
    if (n0w >= NNODES) return;
    const int s0 = start[n0w], s1 = start[n0w + NBW];
    float* AccW = &Acc[w][0][0];

    float bias[6];
#pragma unroll
    for (int ot = 0; ot < 6; ++ot) bias[ot] = be[ot * 16 + l15];

    const float4* a4 = reinterpret_cast<const float4*>(attr);
    const int nt = (s1 - s0 + 15) >> 4;

    if (nt > 0) {
        const int smax = s1 - 1;

        // ---- prologue: tile 0 data (attr + xe) + tile 1 indices ----
        float4 a_cur[6];
        float xe_cur[4][6];
        int2 ss_cur[4], ss_nxt[4];
        int ev_nxt;
        {
            int ev0 = eidx[imin(s0 + l15, smax)];
            const float4* ar = a4 + (size_t)ev0 * NF4 + l4 * 2;
            a_cur[0] = ar[0];  a_cur[1] = ar[1];
            a_cur[2] = ar[8];  a_cur[3] = ar[9];
            a_cur[4] = ar[16]; a_cur[5] = ar[17];
            ev_nxt = eidx[imin(s0 + 16 + l15, smax)];
#pragma unroll
            for (int r = 0; r < 4; ++r) {
                ss_cur[r] = ss_g[imin(s0 + l4 * 4 + r, smax)];
                ss_nxt[r] = ss_g[imin(s0 + 16 + l4 * 4 + r, smax)];
            }
#pragma unroll
            for (int r = 0; r < 4; ++r) {
                const float* xr = x + (size_t)ss_cur[r].x * NF + l15;
#pragma unroll
                for (int ot = 0; ot < 6; ++ot) xe_cur[r][ot] = xr[ot * 16];
            }
        }

        for (int tt = 0; tt < nt; ++tt) {
            const int base = s0 + 16 * tt;

            // ---- 1. consume current attr regs ----
            bf16x8 af[3];
            af[0] = cvt8(a_cur[0], a_cur[1]);
            af[1] = cvt8(a_cur[2], a_cur[3]);
            af[2] = cvt8(a_cur[4], a_cur[5]);

            // ---- 2. reissue attr loads for tile tt+1 (unconditional) ----
            {
                const float4* ar = a4 + (size_t)ev_nxt * NF4 + l4 * 2;
                a_cur[0] = ar[0];  a_cur[1] = ar[1];
                a_cur[2] = ar[8];  a_cur[3] = ar[9];
                a_cur[4] = ar[16]; a_cur[5] = ar[17];
            }

            // ---- 3. eidx for tile tt+2 ----
            ev_nxt = eidx[imin(base + 32 + l15, smax)];

            // ---- 4. current masks; prefetch xe for tile tt+1 (ss_nxt) ----
            int m[4];
#pragma unroll
            for (int r = 0; r < 4; ++r)
                m[r] = ((base + l4 * 4 + r) < s1) ? (ss_cur[r].y - n0w) : -1;

            float xe_nxt[4][6];
#pragma unroll
            for (int r = 0; r < 4; ++r) {
                const float* xr = x + (size_t)ss_nxt[r].x * NF + l15;
#pragma unroll
                for (int ot = 0; ot < 6; ++ot) xe_nxt[r][ot] = xr[ot * 16];
            }

            // ---- 5. rotate index state; load tile tt+2 indices ----
#pragma unroll
            for (int r = 0; r < 4; ++r) ss_cur[r] = ss_nxt[r];
#pragma unroll
            for (int r = 0; r < 4; ++r)
                ss_nxt[r] = ss_g[imin(base + 32 + l4 * 4 + r, smax)];

            // ---- 6. 18 MFMA: D[e][o] ----
            f32x4 acc[6];
#pragma unroll
            for (int ot = 0; ot < 6; ++ot) {
                f32x4 c = {bias[ot], bias[ot], bias[ot], bias[ot]};
#pragma unroll
                for (int kb = 0; kb < 3; ++kb) {
                    bf16x8 bf = *reinterpret_cast<const bf16x8*>(
                        &Wlds[((ot * 3 + kb) * 64 + lane) * 8]);
                    c = __builtin_amdgcn_mfma_f32_16x16x32_bf16(af[kb], bf, c,
                                                                0, 0, 0);
                }
                acc[ot] = c;
            }

            // ---- 7. epilogue: relu + in-lane segmented reduce + ds_add ----
            const bool c1 = (m[1] == m[0]);
            const bool c2 = (m[2] == m[1]);
            const bool c3 = (m[3] == m[2]);
#pragma unroll
            for (int ot = 0; ot < 6; ++ot) {
                const int o = ot * 16 + l15;
                float v0 = fmaxf(acc[ot][0] + xe_cur[0][ot], 0.f);
                float v1 = fmaxf(acc[ot][1] + xe_cur[1][ot], 0.f);
                float v2 = fmaxf(acc[ot][2] + xe_cur[2][ot], 0.f);
                float v3 = fmaxf(acc[ot][3] + xe_cur[3][ot], 0.f);
                float run = v0;
                if (!c1) {
                    if (m[0] >= 0) atomicAdd(&AccW[m[0] * ACC_STRIDE + o], run);
                    run = 0.f;
                }
                run += v1;
                if (!c2) {
                    if (m[1] >= 0) atomicAdd(&AccW[m[1] * ACC_STRIDE + o], run);
                    run = 0.f;
                }
                run += v2;
                if (!c3) {
                    if (m[2] >= 0) atomicAdd(&AccW[m[2] * ACC_STRIDE + o], run);
                    run = 0.f;
                }
                run += v3;
                if (m[3] >= 0) atomicAdd(&AccW[m[3] * ACC_STRIDE + o], run);
            }

            // ---- 8. rotate xe ----
#pragma unroll
            for (int r = 0; r < 4; ++r)
#pragma unroll
                for (int ot = 0; ot < 6; ++ot) xe_cur[r][ot] = xe_nxt[r][ot];
        }
    }

    // ---- drain this wave's ds_adds, then write h (wave-private) ----
    asm volatile("s_waitcnt lgkmcnt(0)" ::: "memory");
    __builtin_amdgcn_sched_barrier(0);
    const float ep = 1.0f + *epsp;
#pragma unroll
    for (int i = 0; i < NBW * NF / 64; ++i) {  // 12
        int item = lane + 64 * i;
        int n = item / NF, f = item % NF;
        float a = AccW[n * ACC_STRIDE + f];
        size_t g = (size_t)(n0w + n) * NF + f;
        h[g] = fmaf(ep, x[g], a);
    }
}

// ---------------------------------------------------------------------------
// Node MLP via bf16 MFMA. Wave owns NPW=16 nodes (contiguous, dense rows).
//   GEMM1: A = h rows (cvt bf16), B = W1pack (LDS) -> h1[16n][96o]
//   relu -> LDS transpose T -> A2 frags -> GEMM2 vs W2pack -> out
// ---------------------------------------------------------------------------
__global__ __launch_bounds__(256) void node_mfma(
    const float* __restrict__ h, const unsigned short* __restrict__ W1p,
    const float* __restrict__ b1, const unsigned short* __restrict__ W2p,
    const float* __restrict__ b2, float* __restrict__ out) {
    __shared__ short W1lds[18 * 64 * 8];          // 18,432 B
    __shared__ short W2lds[18 * 64 * 8];          // 18,432 B
    __shared__ float T[4][NPW][TSTRIDE];          // 25,600 B

    const int t = threadIdx.x;
    {
        const uint4* s1v = reinterpret_cast<const uint4*>(W1p);
        const uint4* s2v = reinterpret_cast<const uint4*>(W2p);
        uint4* d1 = reinterpret_cast<uint4*>(W1lds);
        uint4* d2 = reinterpret_cast<uint4*>(W2lds);
        for (int i = t; i < 18 * 64; i += 256) { d1[i] = s1v[i]; d2[i] = s2v[i]; }
    }
    __syncthreads();

    const int w = t >> 6;
    const int lane = t & 63;
    const int l15 = lane & 15, l4 = lane >> 4;
    const int n0 = (blockIdx.x * 4 + w) * NPW;
    if (n0 >= NNODES) return;

    // A-frags: h row n0+l15, k-span kb*32 + l4*8
    const float4* hrow = reinterpret_cast<const float4*>(h + (size_t)(n0 + l15) * NF);
    bf16x8 af[3];
#pragma unroll
    for (int kb = 0; kb < 3; ++kb)
        af[kb] = cvt8(hrow[kb * 8 + l4 * 2], hrow[kb * 8 + l4 * 2 + 1]);

    // GEMM1 + relu -> T
    float* Tw = &T[w][0][0];
#pragma unroll
    for (int ot = 0; ot < 6; ++ot) {
        float b = b1[ot * 16 + l15];
        f32x4 c = {b, b, b, b};
#pragma unroll
        for (int kb = 0; kb < 3; ++kb) {
            bf16x8 bf = *reinterpret_cast<const bf16x8*>(
                &W1lds[((ot * 3 + kb) * 64 + lane) * 8]);
            c = __builtin_amdgcn_mfma_f32_16x16x32_bf16(af[kb], bf, c, 0, 0, 0);
        }
#pragma unroll
        for (int r = 0; r < 4; ++r)
            Tw[(l4 * 4 + r) * TSTRIDE + ot * 16 + l15] = fmaxf(c[r], 0.f);
    }

    // wave-local LDS write->read ordering
    asm volatile("s_waitcnt lgkmcnt(0)" ::: "memory");
    __builtin_amdgcn_sched_barrier(0);

    // A2-frags from T (row l15), then GEMM2 -> out
    bf16x8 af2[3];
#pragma unroll
    for (int kb = 0; kb < 3; ++kb) {
        const float4* tr = reinterpret_cast<const float4*>(
            &Tw[l15 * TSTRIDE + kb * 32 + l4 * 8]);
        af2[kb] = cvt8(tr[0], tr[1]);
    }
#pragma unroll
    for (int ot = 0; ot < 6; ++ot) {
        float b = b2[ot * 16 + l15];
        f32x4 c = {b, b, b, b};
#pragma unroll
        for (int kb = 0; kb < 3; ++kb) {
            bf16x8 bf = *reinterpret_cast<const bf16x8*>(
                &W2lds[((ot * 3 + kb) * 64 + lane) * 8]);
            c = __builtin_amdgcn_mfma_f32_16x16x32_bf16(af2[kb], bf, c, 0, 0, 0);
        }
#pragma unroll
        for (int r = 0; r < 4; ++r)
            out[(size_t)(n0 + l4 * 4 + r) * NF + ot * 16 + l15] = c[r];
    }
}

// ---------------------------------------------------------------------------
extern "C" void kernel_launch(void* const* d_in, const int* in_sizes, int n_in,
                              void* d_out, int out_size, void* d_ws, size_t ws_size,
                              hipStream_t stream) {
    const float* x   = (const float*)d_in[0];
    const int*   ei  = (const int*)d_in[1];
    const float* ea  = (const float*)d_in[2];
    const float* We  = (const float*)d_in[3];
    const float* be  = (const float*)d_in[4];
    const float* eps = (const float*)d_in[5];
    const float* W1  = (const float*)d_in[6];
    const float* b1  = (const float*)d_in[7];
    const float* W2  = (const float*)d_in[8];
    const float* b2  = (const float*)d_in[9];
    float* out = (float*)d_out;

    // ws layout
    float* h    = (float*)d_ws;                          // 50000*96 f (19.2 MB)
    unsigned short* Wep = (unsigned short*)(h + (size_t)NNODES * NF);  // 9216
    unsigned short* W1p = Wep + 18 * 64 * 8;             // 9216
    unsigned short* W2p = W1p + 18 * 64 * 8;             // 9216
    int* deg    = (int*)(W2p + 18 * 64 * 8);             // 50000
    int* start  = deg + NNODES;                          // 50001
    int* cursor = start + NNODES + 1;                    // 50000
    int* eidx   = cursor + NNODES;                       // 800000 (+pad)
    int2* ss    = (int2*)(eidx + NEDGES + 64);           // 800000 int2 (+pad)
    int* bsum   = (int*)(ss + NEDGES + 64);              // 256
    int* bstart = bsum + 256;                            // 256

    hipMemsetAsync(deg, 0, NNODES * sizeof(int), stream);
    prep_hist<<<3 + (NEDGES + 255) / 256, 256, 0, stream>>>(We, W1, W2, Wep, W1p,
                                                            W2p, ei, deg);
    scan_partial<<<SCAN_BLOCKS, 256, 0, stream>>>(deg, bsum);
    scan_bsum<<<1, 256, 0, stream>>>(bsum, bstart);
    scan_write<<<SCAN_BLOCKS, 256, 0, stream>>>(deg, bstart, start, cursor);
    fill_kernel<<<(NEDGES + 255) / 256, 256, 0, stream>>>(ei, cursor, eidx, ss);
    int nwaves = (NNODES + NBW - 1) / NBW;               // 6250
    int nblocks = (nwaves + WPB - 1) / WPB;              // 1563
    fused_edge_aggr<<<nblocks, 256, 0, stream>>>(ea, eidx, ss, start, x,
                                                 Wep, be, eps, h);
    int nwaves2 = (NNODES + NPW - 1) / NPW;              // 3125
    int nblocks2 = (nwaves2 + 3) / 4;                    // 782
    node_mfma<<<nblocks2, 256, 0, stream>>>(h, W1p, b1, W2p, b2, out);
}

// Round 12
// 273.355 us; speedup vs baseline: 1.1631x; 1.0084x over previous
//
#include <hip/hip_runtime.h>

#define NNODES 50000
#define NEDGES 800000
#define NF 96
#define NF4 24              // float4 per f32 row
#define NBW 4               // nodes per wave (fused): 12500 waves total
#define WPB 4               // waves per block (256 threads)
#define ACC_STRIDE 97       // Acc row stride (floats)
#define NPW 16              // nodes per wave (node MLP)
#define TSTRIDE 100         // h1 transpose tile stride (floats, 16B-aligned)

typedef short bf16x8 __attribute__((ext_vector_type(8)));
typedef float f32x4 __attribute__((ext_vector_type(4)));

__device__ inline unsigned pk_bf16(float a, float b) {
    union { __bf16 h[2]; unsigned u; } q;
    q.h[0] = (__bf16)a; q.h[1] = (__bf16)b;
    return q.u;
}
__device__ inline unsigned short bf16_1(float a) {
    union { __bf16 h; unsigned short u; } q;
    q.h = (__bf16)a;
    return q.u;
}
__device__ inline bf16x8 cvt8(float4 a, float4 b) {
    union { unsigned u[4]; bf16x8 v; } q;
    q.u[0] = pk_bf16(a.x, a.y); q.u[1] = pk_bf16(a.z, a.w);
    q.u[2] = pk_bf16(b.x, b.y); q.u[3] = pk_bf16(b.z, b.w);
    return q.v;
}
__device__ inline int imin(int a, int b) { return a < b ? a : b; }

// ---------------------------------------------------------------------------
// prep: blocks 0/1/2 pack We/W1/W2 into MFMA B-fragment order (bf16);
// remaining blocks do the dst histogram.
// pack[((ot*3+kb)*64+l)*8+j] = bf16(W[(ot*16+(l&15))*96 + kb*32+(l>>4)*8+j])
// ---------------------------------------------------------------------------
__global__ __launch_bounds__(256) void prep_hist(
    const float* __restrict__ We, const float* __restrict__ W1,
    const float* __restrict__ W2, unsigned short* __restrict__ Wep,
    unsigned short* __restrict__ W1p, unsigned short* __restrict__ W2p,
    const int* __restrict__ ei, int* __restrict__ deg) {
    int b = blockIdx.x;
    if (b < 3) {
        const float* S = (b == 0) ? We : (b == 1) ? W1 : W2;
        unsigned short* D = (b == 0) ? Wep : (b == 1) ? W1p : W2p;
        for (int i = threadIdx.x; i < 18 * 64 * 8; i += blockDim.x) {
            int f = i >> 9, rem = i & 511;
            int l = rem >> 3, j = rem & 7;
            int ot = f / 3, kb = f % 3;
            int o = ot * 16 + (l & 15);
            int k = kb * 32 + ((l >> 4) << 3) + j;
            D[i] = bf16_1(S[o * NF + k]);
        }
    } else {
        int e = (b - 3) * 256 + threadIdx.x;
        if (e < NEDGES) atomicAdd(&deg[ei[NEDGES + e]], 1);
    }
}

// ---------------------------------------------------------------------------
// 3-phase multi-block scan + slot fill (int atomics only)
// ---------------------------------------------------------------------------
#define SCAN_BLOCKS 196  // ceil(50000 / 256)

__global__ __launch_bounds__(256) void scan_partial(const int* __restrict__ deg,
                                                    int* __restrict__ bsum) {
    __shared__ int red[256];
    int t = threadIdx.x;
    int i = blockIdx.x * 256 + t;
    red[t] = (i < NNODES) ? deg[i] : 0;
    __syncthreads();
    for (int off = 128; off; off >>= 1) {
        if (t < off) red[t] += red[t + off];
        __syncthreads();
    }
    if (t == 0) bsum[blockIdx.x] = red[0];
}

__global__ __launch_bounds__(256) void scan_bsum(const int* __restrict__ bsum,
                                                 int* __restrict__ bstart) {
    __shared__ int s[256];
    int t = threadIdx.x;
    s[t] = (t < SCAN_BLOCKS) ? bsum[t] : 0;
    __syncthreads();
    for (int off = 1; off < 256; off <<= 1) {
        int v = (t >= off) ? s[t - off] : 0;
        __syncthreads();
        s[t] += v;
        __syncthreads();
    }
    bstart[t] = (t == 0) ? 0 : s[t - 1];  // exclusive
}

__global__ __launch_bounds__(256) void scan_write(const int* __restrict__ deg,
                                                  const int* __restrict__ bstart,
                                                  int* __restrict__ start,
                                                  int* __restrict__ cursor) {
    __shared__ int s[256];
    int t = threadIdx.x;
    int i = blockIdx.x * 256 + t;
    int d = (i < NNODES) ? deg[i] : 0;
    s[t] = d;
    __syncthreads();
    for (int off = 1; off < 256; off <<= 1) {
        int v = (t >= off) ? s[t - off] : 0;
        __syncthreads();
        s[t] += v;
        __syncthreads();
    }
    int excl = ((t == 0) ? 0 : s[t - 1]) + bstart[blockIdx.x];
    if (i < NNODES) {
        start[i] = excl;
        cursor[i] = excl;
        if (i == NNODES - 1) start[NNODES] = excl + d;
    }
}

// fill: eidx[p] = edge id; ss[p] = (src, dst) packed
__global__ void fill_kernel(const int* __restrict__ ei, int* __restrict__ cursor,
                            int* __restrict__ eidx, int2* __restrict__ ss) {
    int e = blockIdx.x * blockDim.x + threadIdx.x;
    if (e < NEDGES) {
        int d = ei[NEDGES + e];
        int p = atomicAdd(&cursor[d], 1);
        eidx[p] = e;
        ss[p] = make_int2(ei[e], d);
    }
}

// ---------------------------------------------------------------------------
// Wave-autonomous fused edge-GEMM + segment-sum, branchless software pipeline.
// R12: NBW=4 (12500 waves -> ~49 waves/CU of work; Acc LDS halved).
// Pipeline state entering iteration tt:
//   a_cur  = attr data, tile tt       ev_nxt  = eidx lanes, tile tt+1
//   ss_cur = (src,dst), tile tt       ss_nxt  = (src,dst), tile tt+1
//   xe_cur = x data, tile tt
// ---------------------------------------------------------------------------
__global__ __launch_bounds__(256) void fused_edge_aggr(
    const float* __restrict__ attr, const int* __restrict__ eidx,
    const int2* __restrict__ ss_g, const int* __restrict__ start,
    const float* __restrict__ x, const unsigned short* __restrict__ Wpack,
    const float* __restrict__ be, const float* __restrict__ epsp,
    float* __restrict__ h) {
    __shared__ short Wlds[18 * 64 * 8];             // 18,432 B
    __shared__ float Acc[WPB][NBW][ACC_STRIDE];     //  6,208 B

    const int t = threadIdx.x;
    {
        const uint4* wsrc = reinterpret_cast<const uint4*>(Wpack);
        uint4* wdst = reinterpret_cast<uint4*>(Wlds);
        for (int i = t; i < 18 * 64; i += 256) wdst[i] = wsrc[i];
        float* accf = &Acc[0][0][0];
        for (int i = t; i < WPB * NBW * ACC_STRIDE; i += 256) accf[i] = 0.f;
    }
    __syncthreads();

    const int w = t >> 6;
    const int lane = t & 63;
    const int l15 = lane & 15, l4 = lane >> 4;
    const int n0w = (blockIdx.x * WPB + w) * NBW;
    if (n0w >= NNODES) return;
    const int s0 = start[n0w], s1 = start[n0w + NBW];
    float* AccW = &Acc[w][0][0];

    float bias[6];
#pragma unroll
    for (int ot = 0; ot < 6; ++ot) bias[ot] = be[ot * 16 + l15];

    const float4* a4 = reinterpret_cast<const float4*>(attr);
    const int nt = (s1 - s0 + 15) >> 4;

    if (nt > 0) {
        const int smax = s1 - 1;

        // ---- prologue: tile 0 data (attr + xe) + tile 1 indices ----
        float4 a_cur[6];
        float xe_cur[4][6];
        int2 ss_cur[4], ss_nxt[4];
        int ev_nxt;
        {
            int ev0 = eidx[imin(s0 + l15, smax)];
            const float4* ar = a4 + (size_t)ev0 * NF4 + l4 * 2;
            a_cur[0] = ar[0];  a_cur[1] = ar[1];
            a_cur[2] = ar[8];  a_cur[3] = ar[9];
            a_cur[4] = ar[16]; a_cur[5] = ar[17];
            ev_nxt = eidx[imin(s0 + 16 + l15, smax)];
#pragma unroll
            for (int r = 0; r < 4; ++r) {
                ss_cur[r] = ss_g[imin(s0 + l4 * 4 + r, smax)];
                ss_nxt[r] = ss_g[imin(s0 + 16 + l4 * 4 + r, smax)];
            }
#pragma unroll
            for (int r = 0; r < 4; ++r) {
                const float* xr = x + (size_t)ss_cur[r].x * NF + l15;
#pragma unroll
                for (int ot = 0; ot < 6; ++ot) xe_cur[r][ot] = xr[ot * 16];
            }
        }

        for (int tt = 0; tt < nt; ++tt) {
            const int base = s0 + 16 * tt;

            // ---- 1. consume current attr regs ----
            bf16x8 af[3];
            af[0] = cvt8(a_cur[0], a_cur[1]);
            af[1] = cvt8(a_cur[2], a_cur[3]);
            af[2] = cvt8(a_cur[4], a_cur[5]);

            // ---- 2. reissue attr loads for tile tt+1 (unconditional) ----
            {
                const float4* ar = a4 + (size_t)ev_nxt * NF4 + l4 * 2;
                a_cur[0] = ar[0];  a_cur[1] = ar[1];
                a_cur[2] = ar[8];  a_cur[3] = ar[9];
                a_cur[4] = ar[16]; a_cur[5] = ar[17];
            }

            // ---- 3. eidx for tile tt+2 ----
            ev_nxt = eidx[imin(base + 32 + l15, smax)];

            // ---- 4. current masks; prefetch xe for tile tt+1 (ss_nxt) ----
            int m[4];
#pragma unroll
            for (int r = 0; r < 4; ++r)
                m[r] = ((base + l4 * 4 + r) < s1) ? (ss_cur[r].y - n0w) : -1;

            float xe_nxt[4][6];
#pragma unroll
            for (int r = 0; r < 4; ++r) {
                const float* xr = x + (size_t)ss_nxt[r].x * NF + l15;
#pragma unroll
                for (int ot = 0; ot < 6; ++ot) xe_nxt[r][ot] = xr[ot * 16];
            }

            // ---- 5. rotate index state; load tile tt+2 indices ----
#pragma unroll
            for (int r = 0; r < 4; ++r) ss_cur[r] = ss_nxt[r];
#pragma unroll
            for (int r = 0; r < 4; ++r)
                ss_nxt[r] = ss_g[imin(base + 32 + l4 * 4 + r, smax)];

            // ---- 6. 18 MFMA: D[e][o] ----
            f32x4 acc[6];
#pragma unroll
            for (int ot = 0; ot < 6; ++ot) {
                f32x4 c = {bias[ot], bias[ot], bias[ot], bias[ot]};
#pragma unroll
                for (int kb = 0; kb < 3; ++kb) {
                    bf16x8 bf = *reinterpret_cast<const bf16x8*>(
                        &Wlds[((ot * 3 + kb) * 64 + lane) * 8]);
                    c = __builtin_amdgcn_mfma_f32_16x16x32_bf16(af[kb], bf, c,
                                                                0, 0, 0);
                }
                acc[ot] = c;
            }

            // ---- 7. epilogue: relu + in-lane segmented reduce + ds_add ----
            const bool c1 = (m[1] == m[0]);
            const bool c2 = (m[2] == m[1]);
            const bool c3 = (m[3] == m[2]);
#pragma unroll
            for (int ot = 0; ot < 6; ++ot) {
                const int o = ot * 16 + l15;
                float v0 = fmaxf(acc[ot][0] + xe_cur[0][ot], 0.f);
                float v1 = fmaxf(acc[ot][1] + xe_cur[1][ot], 0.f);
                float v2 = fmaxf(acc[ot][2] + xe_cur[2][ot], 0.f);
                float v3 = fmaxf(acc[ot][3] + xe_cur[3][ot], 0.f);
                float run = v0;
                if (!c1) {
                    if (m[0] >= 0) atomicAdd(&AccW[m[0] * ACC_STRIDE + o], run);
                    run = 0.f;
                }
                run += v1;
                if (!c2) {
                    if (m[1] >= 0) atomicAdd(&AccW[m[1] * ACC_STRIDE + o], run);
                    run = 0.f;
                }
                run += v2;
                if (!c3) {
                    if (m[2] >= 0) atomicAdd(&AccW[m[2] * ACC_STRIDE + o], run);
                    run = 0.f;
                }
                run += v3;
                if (m[3] >= 0) atomicAdd(&AccW[m[3] * ACC_STRIDE + o], run);
            }

            // ---- 8. rotate xe ----
#pragma unroll
            for (int r = 0; r < 4; ++r)
#pragma unroll
                for (int ot = 0; ot < 6; ++ot) xe_cur[r][ot] = xe_nxt[r][ot];
        }
    }

    // ---- drain this wave's ds_adds, then write h (wave-private) ----
    asm volatile("s_waitcnt lgkmcnt(0)" ::: "memory");
    __builtin_amdgcn_sched_barrier(0);
    const float ep = 1.0f + *epsp;
#pragma unroll
    for (int i = 0; i < NBW * NF / 64; ++i) {  // 6
        int item = lane + 64 * i;
        int n = item / NF, f = item % NF;
        float a = AccW[n * ACC_STRIDE + f];
        size_t g = (size_t)(n0w + n) * NF + f;
        h[g] = fmaf(ep, x[g], a);
    }
}

// ---------------------------------------------------------------------------
// Node MLP via bf16 MFMA. Wave owns NPW=16 nodes (contiguous, dense rows).
//   GEMM1: A = h rows (cvt bf16), B = W1pack (LDS) -> h1[16n][96o]
//   relu -> LDS transpose T -> A2 frags -> GEMM2 vs W2pack -> out
// ---------------------------------------------------------------------------
__global__ __launch_bounds__(256) void node_mfma(
    const float* __restrict__ h, const unsigned short* __restrict__ W1p,
    const float* __restrict__ b1, const unsigned short* __restrict__ W2p,
    const float* __restrict__ b2, float* __restrict__ out) {
    __shared__ short W1lds[18 * 64 * 8];          // 18,432 B
    __shared__ short W2lds[18 * 64 * 8];          // 18,432 B
    __shared__ float T[4][NPW][TSTRIDE];          // 25,600 B

    const int t = threadIdx.x;
    {
        const uint4* s1v = reinterpret_cast<const uint4*>(W1p);
        const uint4* s2v = reinterpret_cast<const uint4*>(W2p);
        uint4* d1 = reinterpret_cast<uint4*>(W1lds);
        uint4* d2 = reinterpret_cast<uint4*>(W2lds);
        for (int i = t; i < 18 * 64; i += 256) { d1[i] = s1v[i]; d2[i] = s2v[i]; }
    }
    __syncthreads();

    const int w = t >> 6;
    const int lane = t & 63;
    const int l15 = lane & 15, l4 = lane >> 4;
    const int n0 = (blockIdx.x * 4 + w) * NPW;
    if (n0 >= NNODES) return;

    // A-frags: h row n0+l15, k-span kb*32 + l4*8
    const float4* hrow = reinterpret_cast<const float4*>(h + (size_t)(n0 + l15) * NF);
    bf16x8 af[3];
#pragma unroll
    for (int kb = 0; kb < 3; ++kb)
        af[kb] = cvt8(hrow[kb * 8 + l4 * 2], hrow[kb * 8 + l4 * 2 + 1]);

    // GEMM1 + relu -> T
    float* Tw = &T[w][0][0];
#pragma unroll
    for (int ot = 0; ot < 6; ++ot) {
        float b = b1[ot * 16 + l15];
        f32x4 c = {b, b, b, b};
#pragma unroll
        for (int kb = 0; kb < 3; ++kb) {
            bf16x8 bf = *reinterpret_cast<const bf16x8*>(
                &W1lds[((ot * 3 + kb) * 64 + lane) * 8]);
            c = __builtin_amdgcn_mfma_f32_16x16x32_bf16(af[kb], bf, c, 0, 0, 0);
        }
#pragma unroll
        for (int r = 0; r < 4; ++r)
            Tw[(l4 * 4 + r) * TSTRIDE + ot * 16 + l15] = fmaxf(c[r], 0.f);
    }

    // wave-local LDS write->read ordering
    asm volatile("s_waitcnt lgkmcnt(0)" ::: "memory");
    __builtin_amdgcn_sched_barrier(0);

    // A2-frags from T (row l15), then GEMM2 -> out
    bf16x8 af2[3];
#pragma unroll
    for (int kb = 0; kb < 3; ++kb) {
        const float4* tr = reinterpret_cast<const float4*>(
            &Tw[l15 * TSTRIDE + kb * 32 + l4 * 8]);
        af2[kb] = cvt8(tr[0], tr[1]);
    }
#pragma unroll
    for (int ot = 0; ot < 6; ++ot) {
        float b = b2[ot * 16 + l15];
        f32x4 c = {b, b, b, b};
#pragma unroll
        for (int kb = 0; kb < 3; ++kb) {
            bf16x8 bf = *reinterpret_cast<const bf16x8*>(
                &W2lds[((ot * 3 + kb) * 64 + lane) * 8]);
            c = __builtin_amdgcn_mfma_f32_16x16x32_bf16(af2[kb], bf, c, 0, 0, 0);
        }
#pragma unroll
        for (int r = 0; r < 4; ++r)
            out[(size_t)(n0 + l4 * 4 + r) * NF + ot * 16 + l15] = c[r];
    }
}

// ---------------------------------------------------------------------------
extern "C" void kernel_launch(void* const* d_in, const int* in_sizes, int n_in,
                              void* d_out, int out_size, void* d_ws, size_t ws_size,
                              hipStream_t stream) {
    const float* x   = (const float*)d_in[0];
    const int*   ei  = (const int*)d_in[1];
    const float* ea  = (const float*)d_in[2];
    const float* We  = (const float*)d_in[3];
    const float* be  = (const float*)d_in[4];
    const float* eps = (const float*)d_in[5];
    const float* W1  = (const float*)d_in[6];
    const float* b1  = (const float*)d_in[7];
    const float* W2  = (const float*)d_in[8];
    const float* b2  = (const float*)d_in[9];
    float* out = (float*)d_out;

    // ws layout
    float* h    = (float*)d_ws;                          // 50000*96 f (19.2 MB)
    unsigned short* Wep = (unsigned short*)(h + (size_t)NNODES * NF);  // 9216
    unsigned short* W1p = Wep + 18 * 64 * 8;             // 9216
    unsigned short* W2p = W1p + 18 * 64 * 8;             // 9216
    int* deg    = (int*)(W2p + 18 * 64 * 8);             // 50000
    int* start  = deg + NNODES;                          // 50001
    int* cursor = start + NNODES + 1;                    // 50000
    int* eidx   = cursor + NNODES;                       // 800000 (+pad)
    int2* ss    = (int2*)(eidx + NEDGES + 64);           // 800000 int2 (+pad)
    int* bsum   = (int*)(ss + NEDGES + 64);              // 256
    int* bstart = bsum + 256;                            // 256

    hipMemsetAsync(deg, 0, NNODES * sizeof(int), stream);
    prep_hist<<<3 + (NEDGES + 255) / 256, 256, 0, stream>>>(We, W1, W2, Wep, W1p,
                                                            W2p, ei, deg);
    scan_partial<<<SCAN_BLOCKS, 256, 0, stream>>>(deg, bsum);
    scan_bsum<<<1, 256, 0, stream>>>(bsum, bstart);
    scan_write<<<SCAN_BLOCKS, 256, 0, stream>>>(deg, bstart, start, cursor);
    fill_kernel<<<(NEDGES + 255) / 256, 256, 0, stream>>>(ei, cursor, eidx, ss);
    int nwaves = (NNODES + NBW - 1) / NBW;               // 12500
    int nblocks = (nwaves + WPB - 1) / WPB;              // 3125
    fused_edge_aggr<<<nblocks, 256, 0, stream>>>(ea, eidx, ss, start, x,
                                                 Wep, be, eps, h);
    int nwaves2 = (NNODES + NPW - 1) / NPW;              // 3125
    int nblocks2 = (nwaves2 + 3) / 4;                    // 782
    node_mfma<<<nblocks2, 256, 0, stream>>>(h, W1p, b1, W2p, b2, out);
}